// Round 3
// baseline (9919.642 us; speedup 1.0000x reference)
//
#include <hip/hip_runtime.h>

typedef _Float16 half8 __attribute__((ext_vector_type(8)));
typedef float f32x4 __attribute__((ext_vector_type(4)));

__device__ __forceinline__ float sigf(float x) { return 1.f / (1.f + __expf(-x)); }
__device__ __forceinline__ float tanhf_(float x) {
  float e = __expf(-2.f * fabsf(x));
  float t = (1.f - e) / (1.f + e);
  return copysignf(t, x);
}

// ---------------- workspace layout (bytes) ----------------
static const size_t O_WGT   = 0;                                  // 2 MB packed Whh f16
static const size_t O_XF16  = O_WGT   + (size_t)2*1024*1024;      // 4096x32 f16
static const size_t O_WIH0P = O_XF16  + 262144;                   // 2x1024x32 f16 (rows permuted)
static const size_t O_B0P   = O_WIH0P + 131072;                   // 2x1024 f32 (permuted)
static const size_t O_WIH1P = O_B0P   + 8192;                     // 2x1024x512 f16 (permuted)
static const size_t O_B1P   = O_WIH1P + 2097152;                  // 2x1024 f32
static const size_t O_W1F   = O_B1P   + 8192;                     // 1024x512 f16
static const size_t O_W2F   = O_W1F   + 1048576;                  // 512x1024 f16
static const size_t O_W3SF  = O_W2F   + 1048576;                  // 1024x512 f16 (W3a+W3b)
static const size_t O_P0    = O_W3SF  + 1048576;                  // 2x4096x1024 f32
static const size_t O_H0    = O_P0    + (size_t)32*1024*1024;     // 4096x512 f16
static const size_t O_P1    = O_H0    + 4194304;                  // 2x4096x1024 f32
static const size_t O_H1    = O_P1    + (size_t)32*1024*1024;     // 4096x512 f16
static const size_t O_M1    = O_H1    + 4194304;                  // 4096x1024 f16
static const size_t O_E     = O_M1    + 8388608;                  // 4096x512 f16
static const size_t O_S     = O_E     + 4194304;                  // 4096x1024 f32
static const size_t WS_NEED = O_S     + (size_t)16*1024*1024;

// ---------------- pack recurrent weights into per-lane MFMA A-fragments ----------------
// Layout: wgt[layer][d][mt 0..63][kc 0..7][lane 0..63] half8.
// M-tile mt covers permuted rows: row m in tile -> unit = mt*4 + (m>>2), gate = m&3,
// original row = gate*256 + unit. A-frag (16x16x32 f16): lane holds
// A[m=lane&15][k = kc*32 + (lane>>4)*8 + j], j=0..7.
__global__ void pack_whh(const float* __restrict__ Whh0, const float* __restrict__ Whh1,
                         half8* __restrict__ wgt) {
  int flat = blockIdx.x * 256 + threadIdx.x;        // [0, 131072)
  int lane = flat & 63;
  int kc   = (flat >> 6) & 7;
  int mt   = (flat >> 9) & 63;
  int d    = (flat >> 15) & 1;
  int layer = flat >> 16;
  int m = lane & 15, q = lane >> 4;
  int ul = mt * 4 + (m >> 2), gate = m & 3;
  int grow = gate * 256 + ul;
  const float* src = (layer ? Whh1 : Whh0) + ((size_t)d * 1024 + grow) * 256 + kc * 32 + q * 8;
  half8 v;
#pragma unroll
  for (int j = 0; j < 8; ++j) v[j] = (_Float16)src[j];
  wgt[flat] = v;
}

// ---------------- pack everything else ----------------
__global__ void pack_misc(const float* __restrict__ v_r, const float* __restrict__ v_l,
                          const float* __restrict__ Wih0, const float* __restrict__ bih0,
                          const float* __restrict__ bhh0, const float* __restrict__ Wih1,
                          const float* __restrict__ bih1, const float* __restrict__ bhh1,
                          const float* __restrict__ W1, const float* __restrict__ W2,
                          const float* __restrict__ W3,
                          _Float16* __restrict__ xf16, _Float16* __restrict__ wih0p,
                          float* __restrict__ b0p, _Float16* __restrict__ wih1p,
                          float* __restrict__ b1p, _Float16* __restrict__ w1f,
                          _Float16* __restrict__ w2f, _Float16* __restrict__ w3sf) {
  int idx = blockIdx.x * 256 + threadIdx.x;
  if (idx < 131072) {                               // X f16 [4096][32], K padded 22->32
    int row = idx >> 5, k = idx & 31;
    float v = 0.f;
    if (k < 22) v = (row < 2048) ? v_r[row * 22 + k] : v_l[(row - 2048) * 22 + k];
    xf16[idx] = (_Float16)v;
    return;
  }
  idx -= 131072;
  if (idx < 65536) {                                // Wih0 permuted rows, K padded
    int d = idx >> 15, jp = (idx >> 5) & 1023, k = idx & 31;
    int u = jp >> 2, g = jp & 3, j = g * 256 + u;
    float v = (k < 22) ? Wih0[((size_t)d * 1024 + j) * 22 + k] : 0.f;
    wih0p[idx] = (_Float16)v;
    return;
  }
  idx -= 65536;
  if (idx < 2048) {                                 // bias0 permuted
    int d = idx >> 10, jp = idx & 1023;
    int u = jp >> 2, g = jp & 3, j = d * 1024 + g * 256 + u;
    b0p[idx] = bih0[j] + bhh0[j];
    return;
  }
  idx -= 2048;
  if (idx < 1048576) {                              // Wih1 permuted rows
    int d = idx >> 19, jp = (idx >> 9) & 1023, k = idx & 511;
    int u = jp >> 2, g = jp & 3;
    wih1p[idx] = (_Float16)Wih1[((size_t)d * 1024 + g * 256 + u) * 512 + k];
    return;
  }
  idx -= 1048576;
  if (idx < 2048) {                                 // bias1 permuted
    int d = idx >> 10, jp = idx & 1023;
    int u = jp >> 2, g = jp & 3, j = d * 1024 + g * 256 + u;
    b1p[idx] = bih1[j] + bhh1[j];
    return;
  }
  idx -= 2048;
  if (idx < 524288) { w1f[idx] = (_Float16)W1[idx]; return; }
  idx -= 524288;
  if (idx < 524288) { w2f[idx] = (_Float16)W2[idx]; return; }
  idx -= 524288;
  if (idx < 524288) {                               // W3s = W3[:, :512] + W3[:, 512:]
    int j = idx >> 9, k = idx & 511;
    w3sf[idx] = (_Float16)(W3[(size_t)j * 1024 + k] + W3[(size_t)j * 1024 + 512 + k]);
    return;
  }
}

// ---------------- generic NT GEMM: C[M,N] = A[M,K]f16 * B[N,K]f16 (+bias)(+relu) ----------------
__global__ __launch_bounds__(256) void gemm_nt(
    const _Float16* __restrict__ A, const _Float16* __restrict__ B,
    const float* __restrict__ bias, void* __restrict__ Cout,
    int N, int K, int do_relu, int f16out, int hasbias) {
  __shared__ _Float16 as[64][40];
  __shared__ _Float16 bs[64][40];
  const int tid = threadIdx.x;
  const int w = tid >> 6, lane = tid & 63, q = lane >> 4, m15 = lane & 15;
  const int bm = blockIdx.x * 64, bn = blockIdx.y * 64;
  const int srow = tid >> 2, spart = tid & 3;
  f32x4 acc[4] = {};
  for (int k0 = 0; k0 < K; k0 += 32) {
    if (k0) __syncthreads();
    *(half8*)&as[srow][spart * 8] = *(const half8*)(A + (size_t)(bm + srow) * K + k0 + spart * 8);
    *(half8*)&bs[srow][spart * 8] = *(const half8*)(B + (size_t)(bn + srow) * K + k0 + spart * 8);
    __syncthreads();
    half8 af = *(const half8*)&as[w * 16 + m15][q * 8];
#pragma unroll
    for (int ns = 0; ns < 4; ++ns) {
      half8 bf = *(const half8*)&bs[ns * 16 + m15][q * 8];
      acc[ns] = __builtin_amdgcn_mfma_f32_16x16x32_f16(af, bf, acc[ns], 0, 0, 0);
    }
  }
#pragma unroll
  for (int ns = 0; ns < 4; ++ns) {
    int gn = bn + ns * 16 + m15;
    float bv = hasbias ? bias[gn] : 0.f;
#pragma unroll
    for (int r = 0; r < 4; ++r) {
      int gm = bm + w * 16 + q * 4 + r;
      float v = acc[ns][r] + bv;
      if (do_relu) v = fmaxf(v, 0.f);
      if (f16out) ((_Float16*)Cout)[(size_t)gm * N + gn] = (_Float16)v;
      else ((float*)Cout)[(size_t)gm * N + gn] = v;
    }
  }
}

// ---------------- recurrent layer: 1 block per direction, all state CU-local ----------------
// 512 threads = 8 waves. Wave w owns M-tiles w*8..w*8+7 (units w*32..w*32+31, all 4 gates).
// Whh kc 0..5 in registers (192 VGPR/lane), kc 6..7 in LDS (128 KB). h double-buffered in LDS.
// __launch_bounds__(512, 1): 1 block/CU -> 2 waves/SIMD -> 256-reg budget; the R2 version
// declared (512,2) which capped at 128 regs and spilled the whole weight array (17 GB
// scratch FETCH per dispatch). A 512-thread block can never exceed 256 regs/wave anyway.
__global__ __launch_bounds__(512, 1) void lstm_layer(
    const half8* __restrict__ wgt,   // this layer's packed Whh (pre-offset)
    const float* __restrict__ P,     // [2 dir][4096 row][1024 jp]  (jp = u*4 + gate)
    _Float16* __restrict__ Hout) {   // [4096][512]  (row = n*2048+t, col = d*256+u)
  extern __shared__ char smem[];
  half8*    lwgt = (half8*)smem;                    // [mt 64][kcl 2][lane 64] = 128 KB
  _Float16* hbuf = (_Float16*)(smem + 131072);      // [2 buf][2 n][288] = 2304 B (288: bank split)
  float4*   gbuf = (float4*)(smem + 133376);        // [2 n][256 unit]        = 8 KB
  const int d = blockIdx.x;
  const int tid = threadIdx.x;
  const int w = tid >> 6, lane = tid & 63;
  const int q = lane >> 4, m15 = lane & 15, n2 = m15 & 1;
  const int uu = tid & 255, nn = tid >> 8;          // update-lane assignment

  half8 Af[8][6];
  {
    const half8* wbase = wgt + ((size_t)(d * 64 + w * 8) * 8) * 64 + lane;
#pragma unroll
    for (int ti = 0; ti < 8; ++ti) {
#pragma unroll
      for (int kc = 0; kc < 6; ++kc) Af[ti][kc] = wbase[(ti * 8 + kc) * 64];
#pragma unroll
      for (int kcl = 0; kcl < 2; ++kcl)
        lwgt[((w * 8 + ti) * 2 + kcl) * 64 + lane] = wbase[(ti * 8 + 6 + kcl) * 64];
    }
  }
  for (int i = tid; i < 1152; i += 512) hbuf[i] = (_Float16)0.f;  // zero both h buffers
  float c = 0.f;
  __syncthreads();

  for (int s = 0; s < 2048; ++s) {
    const int t = d ? (2047 - s) : s;
    const int cur = s & 1, nxt = cur ^ 1;
    // input-part prefetch for this lane's cell (hidden behind the MFMA phase)
    const float4 pv = *(const float4*)(P + ((size_t)(d * 4096 + nn * 2048 + t)) * 1024 + uu * 4);
    f32x4 acc[8] = {};
    const _Float16* hb = hbuf + (cur * 2 + n2) * 288 + q * 8;
#pragma unroll
    for (int kc = 0; kc < 6; ++kc) {
      half8 bf = *(const half8*)(hb + kc * 32);
#pragma unroll
      for (int ti = 0; ti < 8; ++ti)
        acc[ti] = __builtin_amdgcn_mfma_f32_16x16x32_f16(Af[ti][kc], bf, acc[ti], 0, 0, 0);
    }
#pragma unroll
    for (int kcl = 0; kcl < 2; ++kcl) {
      half8 bf = *(const half8*)(hb + (6 + kcl) * 32);
#pragma unroll
      for (int ti = 0; ti < 8; ++ti) {
        half8 wf = lwgt[((w * 8 + ti) * 2 + kcl) * 64 + lane];
        acc[ti] = __builtin_amdgcn_mfma_f32_16x16x32_f16(wf, bf, acc[ti], 0, 0, 0);
      }
    }
    if (m15 < 2) {                                  // task lanes: acc[ti] = 4 gates of one unit
#pragma unroll
      for (int ti = 0; ti < 8; ++ti) {
        int unit = (w * 8 + ti) * 4 + q;
        gbuf[n2 * 256 + unit] = *(const float4*)&acc[ti];
      }
    }
    __syncthreads();
    // cell update: one (chain, unit) per lane, c persistent in-register
    float4 g = gbuf[nn * 256 + uu];
    float xi = g.x + pv.x, xf = g.y + pv.y, xg = g.z + pv.z, xo = g.w + pv.w;
    float cn = sigf(xf) * c + sigf(xi) * tanhf_(xg);
    c = cn;
    float h = sigf(xo) * tanhf_(cn);
    hbuf[(nxt * 2 + nn) * 288 + uu] = (_Float16)h;
    Hout[(size_t)(nn * 2048 + t) * 512 + d * 256 + uu] = (_Float16)h;
    __syncthreads();
  }
}

// ---------------- pair scorer: one wave per pair ----------------
__global__ __launch_bounds__(256) void pair_kernel(
    const float* __restrict__ S, const int* __restrict__ pair_r, const int* __restrict__ pair_l,
    const float* __restrict__ b3, const float* __restrict__ Wout, const float* __restrict__ bout,
    float* __restrict__ out) {
  const int wid = blockIdx.x * 4 + (threadIdx.x >> 6);
  const int lane = threadIdx.x & 63;
  const int r = pair_r[wid], l = pair_l[wid];
  const float* sr = S + (size_t)r * 1024;
  const float* sl = S + (size_t)(2048 + l) * 1024;
  float a0 = 0.f, a1 = 0.f;
#pragma unroll
  for (int cch = 0; cch < 4; ++cch) {
    int j = cch * 256 + lane * 4;
    float4 vr = *(const float4*)(sr + j);
    float4 vl = *(const float4*)(sl + j);
    float4 bb = *(const float4*)(b3 + j);
    float4 w0 = *(const float4*)(Wout + j);
    float4 w1 = *(const float4*)(Wout + 1024 + j);
    float v;
    v = fmaxf(0.f, 0.5f * (vr.x + vl.x) + bb.x); a0 += v * w0.x; a1 += v * w1.x;
    v = fmaxf(0.f, 0.5f * (vr.y + vl.y) + bb.y); a0 += v * w0.y; a1 += v * w1.y;
    v = fmaxf(0.f, 0.5f * (vr.z + vl.z) + bb.z); a0 += v * w0.z; a1 += v * w1.z;
    v = fmaxf(0.f, 0.5f * (vr.w + vl.w) + bb.w); a0 += v * w0.w; a1 += v * w1.w;
  }
#pragma unroll
  for (int off = 32; off; off >>= 1) {
    a0 += __shfl_xor(a0, off, 64);
    a1 += __shfl_xor(a1, off, 64);
  }
  if (lane == 0) {
    float l0 = a0 + bout[0], l1 = a1 + bout[1];
    float m = fmaxf(l0, l1);
    float lse = m + logf(__expf(l0 - m) + __expf(l1 - m));
    out[(size_t)wid * 2] = l0 - lse;
    out[(size_t)wid * 2 + 1] = l1 - lse;
  }
}

extern "C" void kernel_launch(void* const* d_in, const int* in_sizes, int n_in,
                              void* d_out, int out_size, void* d_ws, size_t ws_size,
                              hipStream_t stream) {
  (void)in_sizes; (void)n_in; (void)out_size;
  const float* v_r  = (const float*)d_in[0];
  const float* v_l  = (const float*)d_in[1];
  const int* pair_r = (const int*)d_in[2];
  const int* pair_l = (const int*)d_in[3];
  const float* Wih0 = (const float*)d_in[4];
  const float* Whh0 = (const float*)d_in[5];
  const float* bih0 = (const float*)d_in[6];
  const float* bhh0 = (const float*)d_in[7];
  const float* Wih1 = (const float*)d_in[8];
  const float* Whh1 = (const float*)d_in[9];
  const float* bih1 = (const float*)d_in[10];
  const float* bhh1 = (const float*)d_in[11];
  const float* W1   = (const float*)d_in[12];
  const float* b1   = (const float*)d_in[13];
  const float* W2   = (const float*)d_in[14];
  const float* b2   = (const float*)d_in[15];
  const float* W3   = (const float*)d_in[16];
  const float* b3   = (const float*)d_in[17];
  const float* Wout = (const float*)d_in[18];
  const float* bout = (const float*)d_in[19];

  if (ws_size < WS_NEED) return;
  char* ws = (char*)d_ws;
  half8* wgt      = (half8*)(ws + O_WGT);
  _Float16* xf16  = (_Float16*)(ws + O_XF16);
  _Float16* wih0p = (_Float16*)(ws + O_WIH0P);
  float* b0p      = (float*)(ws + O_B0P);
  _Float16* wih1p = (_Float16*)(ws + O_WIH1P);
  float* b1p      = (float*)(ws + O_B1P);
  _Float16* w1f   = (_Float16*)(ws + O_W1F);
  _Float16* w2f   = (_Float16*)(ws + O_W2F);
  _Float16* w3sf  = (_Float16*)(ws + O_W3SF);
  float* p0       = (float*)(ws + O_P0);
  _Float16* h0    = (_Float16*)(ws + O_H0);
  float* p1       = (float*)(ws + O_P1);
  _Float16* h1    = (_Float16*)(ws + O_H1);
  _Float16* m1    = (_Float16*)(ws + O_M1);
  _Float16* e     = (_Float16*)(ws + O_E);
  float* sbuf     = (float*)(ws + O_S);

  static bool attr_done = false;
  if (!attr_done) {
    (void)hipFuncSetAttribute((const void*)lstm_layer,
                              hipFuncAttributeMaxDynamicSharedMemorySize, 141568);
    attr_done = true;
  }

  pack_whh<<<512, 256, 0, stream>>>(Whh0, Whh1, wgt);
  pack_misc<<<11024, 256, 0, stream>>>(v_r, v_l, Wih0, bih0, bhh0, Wih1, bih1, bhh1,
                                       W1, W2, W3, xf16, wih0p, b0p, wih1p, b1p, w1f, w2f, w3sf);
  // layer-0 input parts (both chains stacked as 4096 rows)
  gemm_nt<<<dim3(64, 16), 256, 0, stream>>>(xf16, wih0p, b0p, p0, 1024, 32, 0, 0, 1);
  gemm_nt<<<dim3(64, 16), 256, 0, stream>>>(xf16, wih0p + 32768, b0p + 1024,
                                            p0 + (size_t)4096 * 1024, 1024, 32, 0, 0, 1);
  lstm_layer<<<2, 512, 141568, stream>>>(wgt, p0, h0);
  // layer-1 input parts
  gemm_nt<<<dim3(64, 16), 256, 0, stream>>>(h0, wih1p, b1p, p1, 1024, 512, 0, 0, 1);
  gemm_nt<<<dim3(64, 16), 256, 0, stream>>>(h0, wih1p + 524288, b1p + 1024,
                                            p1 + (size_t)4096 * 1024, 1024, 512, 0, 0, 1);
  lstm_layer<<<2, 512, 141568, stream>>>(wgt + 65536, p1, h1);
  // MLP + symmetrized pair rep precompute
  gemm_nt<<<dim3(64, 16), 256, 0, stream>>>(h1, w1f, b1, m1, 1024, 512, 1, 1, 1);
  gemm_nt<<<dim3(64, 8), 256, 0, stream>>>(m1, w2f, b2, e, 512, 1024, 1, 1, 1);
  gemm_nt<<<dim3(64, 16), 256, 0, stream>>>(e, w3sf, nullptr, sbuf, 1024, 512, 0, 0, 0);
  pair_kernel<<<16384, 256, 0, stream>>>(sbuf, pair_r, pair_l, b3, Wout, bout, (float*)d_out);
}

// Round 4
// 9918.494 us; speedup vs baseline: 1.0001x; 1.0001x over previous
//
#include <hip/hip_runtime.h>

typedef _Float16 half8 __attribute__((ext_vector_type(8)));
typedef float f32x4 __attribute__((ext_vector_type(4)));

__device__ __forceinline__ float sigf(float x) { return 1.f / (1.f + __expf(-x)); }
__device__ __forceinline__ float tanhf_(float x) {
  float e = __expf(-2.f * fabsf(x));
  float t = (1.f - e) / (1.f + e);
  return copysignf(t, x);
}

// ---------------- workspace layout (bytes) ----------------
static const size_t O_WGT   = 0;                                  // 2 MB packed Whh f16
static const size_t O_XF16  = O_WGT   + (size_t)2*1024*1024;      // 4096x32 f16
static const size_t O_WIH0P = O_XF16  + 262144;                   // 2x1024x32 f16 (rows permuted)
static const size_t O_B0P   = O_WIH0P + 131072;                   // 2x1024 f32 (permuted)
static const size_t O_WIH1P = O_B0P   + 8192;                     // 2x1024x512 f16 (permuted)
static const size_t O_B1P   = O_WIH1P + 2097152;                  // 2x1024 f32
static const size_t O_W1F   = O_B1P   + 8192;                     // 1024x512 f16
static const size_t O_W2F   = O_W1F   + 1048576;                  // 512x1024 f16
static const size_t O_W3SF  = O_W2F   + 1048576;                  // 1024x512 f16 (W3a+W3b)
static const size_t O_P0    = O_W3SF  + 1048576;                  // 2x4096x1024 f32
static const size_t O_H0    = O_P0    + (size_t)32*1024*1024;     // 4096x512 f16
static const size_t O_P1    = O_H0    + 4194304;                  // 2x4096x1024 f32
static const size_t O_H1    = O_P1    + (size_t)32*1024*1024;     // 4096x512 f16
static const size_t O_M1    = O_H1    + 4194304;                  // 4096x1024 f16
static const size_t O_E     = O_M1    + 8388608;                  // 4096x512 f16
static const size_t O_S     = O_E     + 4194304;                  // 4096x1024 f32
static const size_t WS_NEED = O_S     + (size_t)16*1024*1024;

// ---------------- pack recurrent weights into per-lane MFMA A-fragments ----------------
// Layout: wgt[layer][d][mt 0..63][kc 0..7][lane 0..63] half8.
// M-tile mt covers permuted rows: row m in tile -> unit = mt*4 + (m>>2), gate = m&3,
// original row = gate*256 + unit. A-frag (16x16x32 f16): lane holds
// A[m=lane&15][k = kc*32 + (lane>>4)*8 + j], j=0..7.
__global__ void pack_whh(const float* __restrict__ Whh0, const float* __restrict__ Whh1,
                         half8* __restrict__ wgt) {
  int flat = blockIdx.x * 256 + threadIdx.x;        // [0, 131072)
  int lane = flat & 63;
  int kc   = (flat >> 6) & 7;
  int mt   = (flat >> 9) & 63;
  int d    = (flat >> 15) & 1;
  int layer = flat >> 16;
  int m = lane & 15, q = lane >> 4;
  int ul = mt * 4 + (m >> 2), gate = m & 3;
  int grow = gate * 256 + ul;
  const float* src = (layer ? Whh1 : Whh0) + ((size_t)d * 1024 + grow) * 256 + kc * 32 + q * 8;
  half8 v;
#pragma unroll
  for (int j = 0; j < 8; ++j) v[j] = (_Float16)src[j];
  wgt[flat] = v;
}

// ---------------- pack everything else ----------------
__global__ void pack_misc(const float* __restrict__ v_r, const float* __restrict__ v_l,
                          const float* __restrict__ Wih0, const float* __restrict__ bih0,
                          const float* __restrict__ bhh0, const float* __restrict__ Wih1,
                          const float* __restrict__ bih1, const float* __restrict__ bhh1,
                          const float* __restrict__ W1, const float* __restrict__ W2,
                          const float* __restrict__ W3,
                          _Float16* __restrict__ xf16, _Float16* __restrict__ wih0p,
                          float* __restrict__ b0p, _Float16* __restrict__ wih1p,
                          float* __restrict__ b1p, _Float16* __restrict__ w1f,
                          _Float16* __restrict__ w2f, _Float16* __restrict__ w3sf) {
  int idx = blockIdx.x * 256 + threadIdx.x;
  if (idx < 131072) {                               // X f16 [4096][32], K padded 22->32
    int row = idx >> 5, k = idx & 31;
    float v = 0.f;
    if (k < 22) v = (row < 2048) ? v_r[row * 22 + k] : v_l[(row - 2048) * 22 + k];
    xf16[idx] = (_Float16)v;
    return;
  }
  idx -= 131072;
  if (idx < 65536) {                                // Wih0 permuted rows, K padded
    int d = idx >> 15, jp = (idx >> 5) & 1023, k = idx & 31;
    int u = jp >> 2, g = jp & 3, j = g * 256 + u;
    float v = (k < 22) ? Wih0[((size_t)d * 1024 + j) * 22 + k] : 0.f;
    wih0p[idx] = (_Float16)v;
    return;
  }
  idx -= 65536;
  if (idx < 2048) {                                 // bias0 permuted
    int d = idx >> 10, jp = idx & 1023;
    int u = jp >> 2, g = jp & 3, j = d * 1024 + g * 256 + u;
    b0p[idx] = bih0[j] + bhh0[j];
    return;
  }
  idx -= 2048;
  if (idx < 1048576) {                              // Wih1 permuted rows
    int d = idx >> 19, jp = (idx >> 9) & 1023, k = idx & 511;
    int u = jp >> 2, g = jp & 3;
    wih1p[idx] = (_Float16)Wih1[((size_t)d * 1024 + g * 256 + u) * 512 + k];
    return;
  }
  idx -= 1048576;
  if (idx < 2048) {                                 // bias1 permuted
    int d = idx >> 10, jp = idx & 1023;
    int u = jp >> 2, g = jp & 3, j = d * 1024 + g * 256 + u;
    b1p[idx] = bih1[j] + bhh1[j];
    return;
  }
  idx -= 2048;
  if (idx < 524288) { w1f[idx] = (_Float16)W1[idx]; return; }
  idx -= 524288;
  if (idx < 524288) { w2f[idx] = (_Float16)W2[idx]; return; }
  idx -= 524288;
  if (idx < 524288) {                               // W3s = W3[:, :512] + W3[:, 512:]
    int j = idx >> 9, k = idx & 511;
    w3sf[idx] = (_Float16)(W3[(size_t)j * 1024 + k] + W3[(size_t)j * 1024 + 512 + k]);
    return;
  }
}

// ---------------- generic NT GEMM: C[M,N] = A[M,K]f16 * B[N,K]f16 (+bias)(+relu) ----------------
__global__ __launch_bounds__(256) void gemm_nt(
    const _Float16* __restrict__ A, const _Float16* __restrict__ B,
    const float* __restrict__ bias, void* __restrict__ Cout,
    int N, int K, int do_relu, int f16out, int hasbias) {
  __shared__ _Float16 as[64][40];
  __shared__ _Float16 bs[64][40];
  const int tid = threadIdx.x;
  const int w = tid >> 6, lane = tid & 63, q = lane >> 4, m15 = lane & 15;
  const int bm = blockIdx.x * 64, bn = blockIdx.y * 64;
  const int srow = tid >> 2, spart = tid & 3;
  f32x4 acc[4] = {};
  for (int k0 = 0; k0 < K; k0 += 32) {
    if (k0) __syncthreads();
    *(half8*)&as[srow][spart * 8] = *(const half8*)(A + (size_t)(bm + srow) * K + k0 + spart * 8);
    *(half8*)&bs[srow][spart * 8] = *(const half8*)(B + (size_t)(bn + srow) * K + k0 + spart * 8);
    __syncthreads();
    half8 af = *(const half8*)&as[w * 16 + m15][q * 8];
#pragma unroll
    for (int ns = 0; ns < 4; ++ns) {
      half8 bf = *(const half8*)&bs[ns * 16 + m15][q * 8];
      acc[ns] = __builtin_amdgcn_mfma_f32_16x16x32_f16(af, bf, acc[ns], 0, 0, 0);
    }
  }
#pragma unroll
  for (int ns = 0; ns < 4; ++ns) {
    int gn = bn + ns * 16 + m15;
    float bv = hasbias ? bias[gn] : 0.f;
#pragma unroll
    for (int r = 0; r < 4; ++r) {
      int gm = bm + w * 16 + q * 4 + r;
      float v = acc[ns][r] + bv;
      if (do_relu) v = fmaxf(v, 0.f);
      if (f16out) ((_Float16*)Cout)[(size_t)gm * N + gn] = (_Float16)v;
      else ((float*)Cout)[(size_t)gm * N + gn] = v;
    }
  }
}

// ---------------- recurrent layer: 1 block per direction, all state CU-local ----------------
// 512 threads = 8 waves. Wave w owns M-tiles w*8..w*8+7 (units w*32..w*32+31, all 4 gates).
// Whh kc 0..5 as 48 NAMED half8 SSA values (R3's Af[8][6] array was never promoted out of
// scratch -> 17 GB/dispatch spill traffic; named values leave the allocator no alloca to
// abandon). kc 6..7 in LDS (128 KB). h double-buffered in LDS; gate pre-acts redistributed
// through LDS so each of 512 lanes updates one (chain,unit) cell with c in-register.
#define MFMAF(Wf, Bf, Acc) __builtin_amdgcn_mfma_f32_16x16x32_f16((Wf), (Bf), (Acc), 0, 0, 0)
__global__ __launch_bounds__(512) __attribute__((amdgpu_waves_per_eu(2, 2)))
void lstm_layer(
    const half8* __restrict__ wgt,   // this layer's packed Whh (pre-offset)
    const float* __restrict__ P,     // [2 dir][4096 row][1024 jp]  (jp = u*4 + gate)
    _Float16* __restrict__ Hout) {   // [4096][512]  (row = n*2048+t, col = d*256+u)
  extern __shared__ char smem[];
  half8*    lwgt = (half8*)smem;                    // [mt 64][kcl 2][lane 64] = 128 KB
  _Float16* hbuf = (_Float16*)(smem + 131072);      // [2 buf][2 n][288] = 2304 B (288: bank split)
  float4*   gbuf = (float4*)(smem + 133376);        // [2 n][256 unit]        = 8 KB
  const int d = blockIdx.x;
  const int tid = threadIdx.x;
  const int w = tid >> 6, lane = tid & 63;
  const int q = lane >> 4, m15 = lane & 15, n2 = m15 & 1;
  const int uu = tid & 255, nn = tid >> 8;          // update-lane assignment

  const half8* wb = wgt + ((size_t)(d * 64 + w * 8) * 8) * 64 + lane;
#define WLD(ti, kc) wb[((ti) * 8 + (kc)) * 64]
  half8 W0_0=WLD(0,0), W0_1=WLD(0,1), W0_2=WLD(0,2), W0_3=WLD(0,3), W0_4=WLD(0,4), W0_5=WLD(0,5);
  half8 W1_0=WLD(1,0), W1_1=WLD(1,1), W1_2=WLD(1,2), W1_3=WLD(1,3), W1_4=WLD(1,4), W1_5=WLD(1,5);
  half8 W2_0=WLD(2,0), W2_1=WLD(2,1), W2_2=WLD(2,2), W2_3=WLD(2,3), W2_4=WLD(2,4), W2_5=WLD(2,5);
  half8 W3_0=WLD(3,0), W3_1=WLD(3,1), W3_2=WLD(3,2), W3_3=WLD(3,3), W3_4=WLD(3,4), W3_5=WLD(3,5);
  half8 W4_0=WLD(4,0), W4_1=WLD(4,1), W4_2=WLD(4,2), W4_3=WLD(4,3), W4_4=WLD(4,4), W4_5=WLD(4,5);
  half8 W5_0=WLD(5,0), W5_1=WLD(5,1), W5_2=WLD(5,2), W5_3=WLD(5,3), W5_4=WLD(5,4), W5_5=WLD(5,5);
  half8 W6_0=WLD(6,0), W6_1=WLD(6,1), W6_2=WLD(6,2), W6_3=WLD(6,3), W6_4=WLD(6,4), W6_5=WLD(6,5);
  half8 W7_0=WLD(7,0), W7_1=WLD(7,1), W7_2=WLD(7,2), W7_3=WLD(7,3), W7_4=WLD(7,4), W7_5=WLD(7,5);
#pragma unroll
  for (int ti = 0; ti < 8; ++ti) {
    lwgt[((w * 8 + ti) * 2 + 0) * 64 + lane] = WLD(ti, 6);
    lwgt[((w * 8 + ti) * 2 + 1) * 64 + lane] = WLD(ti, 7);
  }
  for (int i = tid; i < 1152; i += 512) hbuf[i] = (_Float16)0.f;  // zero both h buffers
  float c = 0.f;
  __syncthreads();

  for (int s = 0; s < 2048; ++s) {
    const int t = d ? (2047 - s) : s;
    const int cur = s & 1, nxt = cur ^ 1;
    // input-part prefetch for this lane's cell (hidden behind the MFMA phase)
    const float4 pv = *(const float4*)(P + ((size_t)(d * 4096 + nn * 2048 + t)) * 1024 + uu * 4);
    const _Float16* hb = hbuf + (cur * 2 + n2) * 288 + q * 8;
    f32x4 a0 = {}, a1 = {}, a2 = {}, a3 = {}, a4 = {}, a5 = {}, a6 = {}, a7 = {};
#define KCREG(kc) { half8 bf = *(const half8*)(hb + (kc) * 32);            \
    a0 = MFMAF(W0_##kc, bf, a0); a1 = MFMAF(W1_##kc, bf, a1);              \
    a2 = MFMAF(W2_##kc, bf, a2); a3 = MFMAF(W3_##kc, bf, a3);              \
    a4 = MFMAF(W4_##kc, bf, a4); a5 = MFMAF(W5_##kc, bf, a5);              \
    a6 = MFMAF(W6_##kc, bf, a6); a7 = MFMAF(W7_##kc, bf, a7); }
    KCREG(0) KCREG(1) KCREG(2) KCREG(3) KCREG(4) KCREG(5)
#define KCLDS(kcl) { half8 bf = *(const half8*)(hb + (6 + (kcl)) * 32);                  \
    a0 = MFMAF(lwgt[((w * 8 + 0) * 2 + (kcl)) * 64 + lane], bf, a0);                     \
    a1 = MFMAF(lwgt[((w * 8 + 1) * 2 + (kcl)) * 64 + lane], bf, a1);                     \
    a2 = MFMAF(lwgt[((w * 8 + 2) * 2 + (kcl)) * 64 + lane], bf, a2);                     \
    a3 = MFMAF(lwgt[((w * 8 + 3) * 2 + (kcl)) * 64 + lane], bf, a3);                     \
    a4 = MFMAF(lwgt[((w * 8 + 4) * 2 + (kcl)) * 64 + lane], bf, a4);                     \
    a5 = MFMAF(lwgt[((w * 8 + 5) * 2 + (kcl)) * 64 + lane], bf, a5);                     \
    a6 = MFMAF(lwgt[((w * 8 + 6) * 2 + (kcl)) * 64 + lane], bf, a6);                     \
    a7 = MFMAF(lwgt[((w * 8 + 7) * 2 + (kcl)) * 64 + lane], bf, a7); }
    KCLDS(0) KCLDS(1)
    if (m15 < 2) {                                  // task lanes: aN = 4 gates of one unit
      gbuf[n2 * 256 + (w * 8 + 0) * 4 + q] = make_float4(a0[0], a0[1], a0[2], a0[3]);
      gbuf[n2 * 256 + (w * 8 + 1) * 4 + q] = make_float4(a1[0], a1[1], a1[2], a1[3]);
      gbuf[n2 * 256 + (w * 8 + 2) * 4 + q] = make_float4(a2[0], a2[1], a2[2], a2[3]);
      gbuf[n2 * 256 + (w * 8 + 3) * 4 + q] = make_float4(a3[0], a3[1], a3[2], a3[3]);
      gbuf[n2 * 256 + (w * 8 + 4) * 4 + q] = make_float4(a4[0], a4[1], a4[2], a4[3]);
      gbuf[n2 * 256 + (w * 8 + 5) * 4 + q] = make_float4(a5[0], a5[1], a5[2], a5[3]);
      gbuf[n2 * 256 + (w * 8 + 6) * 4 + q] = make_float4(a6[0], a6[1], a6[2], a6[3]);
      gbuf[n2 * 256 + (w * 8 + 7) * 4 + q] = make_float4(a7[0], a7[1], a7[2], a7[3]);
    }
    __syncthreads();
    // cell update: one (chain, unit) per lane, c persistent in-register
    float4 g = gbuf[nn * 256 + uu];
    float xi = g.x + pv.x, xf = g.y + pv.y, xg = g.z + pv.z, xo = g.w + pv.w;
    float cn = sigf(xf) * c + sigf(xi) * tanhf_(xg);
    c = cn;
    float h = sigf(xo) * tanhf_(cn);
    hbuf[(nxt * 2 + nn) * 288 + uu] = (_Float16)h;
    Hout[(size_t)(nn * 2048 + t) * 512 + d * 256 + uu] = (_Float16)h;
    __syncthreads();
  }
}

// ---------------- pair scorer: one wave per pair ----------------
__global__ __launch_bounds__(256) void pair_kernel(
    const float* __restrict__ S, const int* __restrict__ pair_r, const int* __restrict__ pair_l,
    const float* __restrict__ b3, const float* __restrict__ Wout, const float* __restrict__ bout,
    float* __restrict__ out) {
  const int wid = blockIdx.x * 4 + (threadIdx.x >> 6);
  const int lane = threadIdx.x & 63;
  const int r = pair_r[wid], l = pair_l[wid];
  const float* sr = S + (size_t)r * 1024;
  const float* sl = S + (size_t)(2048 + l) * 1024;
  float a0 = 0.f, a1 = 0.f;
#pragma unroll
  for (int cch = 0; cch < 4; ++cch) {
    int j = cch * 256 + lane * 4;
    float4 vr = *(const float4*)(sr + j);
    float4 vl = *(const float4*)(sl + j);
    float4 bb = *(const float4*)(b3 + j);
    float4 w0 = *(const float4*)(Wout + j);
    float4 w1 = *(const float4*)(Wout + 1024 + j);
    float v;
    v = fmaxf(0.f, 0.5f * (vr.x + vl.x) + bb.x); a0 += v * w0.x; a1 += v * w1.x;
    v = fmaxf(0.f, 0.5f * (vr.y + vl.y) + bb.y); a0 += v * w0.y; a1 += v * w1.y;
    v = fmaxf(0.f, 0.5f * (vr.z + vl.z) + bb.z); a0 += v * w0.z; a1 += v * w1.z;
    v = fmaxf(0.f, 0.5f * (vr.w + vl.w) + bb.w); a0 += v * w0.w; a1 += v * w1.w;
  }
#pragma unroll
  for (int off = 32; off; off >>= 1) {
    a0 += __shfl_xor(a0, off, 64);
    a1 += __shfl_xor(a1, off, 64);
  }
  if (lane == 0) {
    float l0 = a0 + bout[0], l1 = a1 + bout[1];
    float m = fmaxf(l0, l1);
    float lse = m + logf(__expf(l0 - m) + __expf(l1 - m));
    out[(size_t)wid * 2] = l0 - lse;
    out[(size_t)wid * 2 + 1] = l1 - lse;
  }
}

extern "C" void kernel_launch(void* const* d_in, const int* in_sizes, int n_in,
                              void* d_out, int out_size, void* d_ws, size_t ws_size,
                              hipStream_t stream) {
  (void)in_sizes; (void)n_in; (void)out_size;
  const float* v_r  = (const float*)d_in[0];
  const float* v_l  = (const float*)d_in[1];
  const int* pair_r = (const int*)d_in[2];
  const int* pair_l = (const int*)d_in[3];
  const float* Wih0 = (const float*)d_in[4];
  const float* Whh0 = (const float*)d_in[5];
  const float* bih0 = (const float*)d_in[6];
  const float* bhh0 = (const float*)d_in[7];
  const float* Wih1 = (const float*)d_in[8];
  const float* Whh1 = (const float*)d_in[9];
  const float* bih1 = (const float*)d_in[10];
  const float* bhh1 = (const float*)d_in[11];
  const float* W1   = (const float*)d_in[12];
  const float* b1   = (const float*)d_in[13];
  const float* W2   = (const float*)d_in[14];
  const float* b2   = (const float*)d_in[15];
  const float* W3   = (const float*)d_in[16];
  const float* b3   = (const float*)d_in[17];
  const float* Wout = (const float*)d_in[18];
  const float* bout = (const float*)d_in[19];

  if (ws_size < WS_NEED) return;
  char* ws = (char*)d_ws;
  half8* wgt      = (half8*)(ws + O_WGT);
  _Float16* xf16  = (_Float16*)(ws + O_XF16);
  _Float16* wih0p = (_Float16*)(ws + O_WIH0P);
  float* b0p      = (float*)(ws + O_B0P);
  _Float16* wih1p = (_Float16*)(ws + O_WIH1P);
  float* b1p      = (float*)(ws + O_B1P);
  _Float16* w1f   = (_Float16*)(ws + O_W1F);
  _Float16* w2f   = (_Float16*)(ws + O_W2F);
  _Float16* w3sf  = (_Float16*)(ws + O_W3SF);
  float* p0       = (float*)(ws + O_P0);
  _Float16* h0    = (_Float16*)(ws + O_H0);
  float* p1       = (float*)(ws + O_P1);
  _Float16* h1    = (_Float16*)(ws + O_H1);
  _Float16* m1    = (_Float16*)(ws + O_M1);
  _Float16* e     = (_Float16*)(ws + O_E);
  float* sbuf     = (float*)(ws + O_S);

  (void)hipFuncSetAttribute((const void*)lstm_layer,
                            hipFuncAttributeMaxDynamicSharedMemorySize, 141568);

  pack_whh<<<512, 256, 0, stream>>>(Whh0, Whh1, wgt);
  pack_misc<<<11024, 256, 0, stream>>>(v_r, v_l, Wih0, bih0, bhh0, Wih1, bih1, bhh1,
                                       W1, W2, W3, xf16, wih0p, b0p, wih1p, b1p, w1f, w2f, w3sf);
  // layer-0 input parts (both chains stacked as 4096 rows)
  gemm_nt<<<dim3(64, 16), 256, 0, stream>>>(xf16, wih0p, b0p, p0, 1024, 32, 0, 0, 1);
  gemm_nt<<<dim3(64, 16), 256, 0, stream>>>(xf16, wih0p + 32768, b0p + 1024,
                                            p0 + (size_t)4096 * 1024, 1024, 32, 0, 0, 1);
  lstm_layer<<<2, 512, 141568, stream>>>(wgt, p0, h0);
  // layer-1 input parts
  gemm_nt<<<dim3(64, 16), 256, 0, stream>>>(h0, wih1p, b1p, p1, 1024, 512, 0, 0, 1);
  gemm_nt<<<dim3(64, 16), 256, 0, stream>>>(h0, wih1p + 524288, b1p + 1024,
                                            p1 + (size_t)4096 * 1024, 1024, 512, 0, 0, 1);
  lstm_layer<<<2, 512, 141568, stream>>>(wgt + 65536, p1, h1);
  // MLP + symmetrized pair rep precompute
  gemm_nt<<<dim3(64, 16), 256, 0, stream>>>(h1, w1f, b1, m1, 1024, 512, 1, 1, 1);
  gemm_nt<<<dim3(64, 8), 256, 0, stream>>>(m1, w2f, b2, e, 512, 1024, 1, 1, 1);
  gemm_nt<<<dim3(64, 16), 256, 0, stream>>>(e, w3sf, nullptr, sbuf, 1024, 512, 0, 0, 0);
  pair_kernel<<<16384, 256, 0, stream>>>(sbuf, pair_r, pair_l, b3, Wout, bout, (float*)d_out);
}

// Round 5
// 6296.504 us; speedup vs baseline: 1.5754x; 1.5752x over previous
//
#include <hip/hip_runtime.h>

typedef _Float16 half8 __attribute__((ext_vector_type(8)));
typedef float f32x4 __attribute__((ext_vector_type(4)));

#define AGENT __HIP_MEMORY_SCOPE_AGENT

__device__ __forceinline__ float sigf(float x) { return 1.f / (1.f + __expf(-x)); }
__device__ __forceinline__ float tanhf_(float x) {
  float e = __expf(-2.f * fabsf(x));
  float t = (1.f - e) / (1.f + e);
  return copysignf(t, x);
}

// ---------------- workspace layout (bytes) ----------------
static const size_t O_WGT   = 0;                                  // 2 MB packed Whh f16
static const size_t O_XF16  = O_WGT   + (size_t)2*1024*1024;      // 4096x32 f16
static const size_t O_WIH0P = O_XF16  + 262144;                   // 2x1024x32 f16 (rows permuted)
static const size_t O_B0P   = O_WIH0P + 131072;                   // 2x1024 f32 (permuted)
static const size_t O_WIH1P = O_B0P   + 8192;                     // 2x1024x512 f16 (permuted)
static const size_t O_B1P   = O_WIH1P + 2097152;                  // 2x1024 f32
static const size_t O_W1F   = O_B1P   + 8192;                     // 1024x512 f16
static const size_t O_W2F   = O_W1F   + 1048576;                  // 512x1024 f16
static const size_t O_W3SF  = O_W2F   + 1048576;                  // 1024x512 f16 (W3a+W3b)
static const size_t O_P0    = O_W3SF  + 1048576;                  // 2x4096x1024 f32
static const size_t O_H0    = O_P0    + (size_t)32*1024*1024;     // 4096x512 f16
static const size_t O_P1    = O_H0    + 4194304;                  // 2x4096x1024 f32
static const size_t O_H1    = O_P1    + (size_t)32*1024*1024;     // 4096x512 f16
static const size_t O_M1    = O_H1    + 4194304;                  // 4096x1024 f16
static const size_t O_E     = O_M1    + 8388608;                  // 4096x512 f16
static const size_t O_S     = O_E     + 4194304;                  // 4096x1024 f32
static const size_t O_XG    = O_S     + (size_t)16*1024*1024;     // 8 KB tagged h-exchange
static const size_t WS_NEED = O_XG    + 8192;

// ---------------- pack recurrent weights into per-lane MFMA A-fragments ----------------
// Layout: wgt[layer][d][mt 0..63][kc 0..7][lane 0..63] half8.
// M-tile mt covers permuted rows: row m in tile -> unit = mt*4 + (m>>2), gate = m&3,
// original row = gate*256 + unit. A-frag (16x16x32 f16): lane holds
// A[m=lane&15][k = kc*32 + (lane>>4)*8 + j], j=0..7.
__global__ void pack_whh(const float* __restrict__ Whh0, const float* __restrict__ Whh1,
                         half8* __restrict__ wgt) {
  int flat = blockIdx.x * 256 + threadIdx.x;        // [0, 131072)
  int lane = flat & 63;
  int kc   = (flat >> 6) & 7;
  int mt   = (flat >> 9) & 63;
  int d    = (flat >> 15) & 1;
  int layer = flat >> 16;
  int m = lane & 15, q = lane >> 4;
  int ul = mt * 4 + (m >> 2), gate = m & 3;
  int grow = gate * 256 + ul;
  const float* src = (layer ? Whh1 : Whh0) + ((size_t)d * 1024 + grow) * 256 + kc * 32 + q * 8;
  half8 v;
#pragma unroll
  for (int j = 0; j < 8; ++j) v[j] = (_Float16)src[j];
  wgt[flat] = v;
}

// ---------------- pack everything else ----------------
__global__ void pack_misc(const float* __restrict__ v_r, const float* __restrict__ v_l,
                          const float* __restrict__ Wih0, const float* __restrict__ bih0,
                          const float* __restrict__ bhh0, const float* __restrict__ Wih1,
                          const float* __restrict__ bih1, const float* __restrict__ bhh1,
                          const float* __restrict__ W1, const float* __restrict__ W2,
                          const float* __restrict__ W3,
                          _Float16* __restrict__ xf16, _Float16* __restrict__ wih0p,
                          float* __restrict__ b0p, _Float16* __restrict__ wih1p,
                          float* __restrict__ b1p, _Float16* __restrict__ w1f,
                          _Float16* __restrict__ w2f, _Float16* __restrict__ w3sf) {
  int idx = blockIdx.x * 256 + threadIdx.x;
  if (idx < 131072) {                               // X f16 [4096][32], K padded 22->32
    int row = idx >> 5, k = idx & 31;
    float v = 0.f;
    if (k < 22) v = (row < 2048) ? v_r[row * 22 + k] : v_l[(row - 2048) * 22 + k];
    xf16[idx] = (_Float16)v;
    return;
  }
  idx -= 131072;
  if (idx < 65536) {                                // Wih0 permuted rows, K padded
    int d = idx >> 15, jp = (idx >> 5) & 1023, k = idx & 31;
    int u = jp >> 2, g = jp & 3, j = g * 256 + u;
    float v = (k < 22) ? Wih0[((size_t)d * 1024 + j) * 22 + k] : 0.f;
    wih0p[idx] = (_Float16)v;
    return;
  }
  idx -= 65536;
  if (idx < 2048) {                                 // bias0 permuted
    int d = idx >> 10, jp = idx & 1023;
    int u = jp >> 2, g = jp & 3, j = d * 1024 + g * 256 + u;
    b0p[idx] = bih0[j] + bhh0[j];
    return;
  }
  idx -= 2048;
  if (idx < 1048576) {                              // Wih1 permuted rows
    int d = idx >> 19, jp = (idx >> 9) & 1023, k = idx & 511;
    int u = jp >> 2, g = jp & 3;
    wih1p[idx] = (_Float16)Wih1[((size_t)d * 1024 + g * 256 + u) * 512 + k];
    return;
  }
  idx -= 1048576;
  if (idx < 2048) {                                 // bias1 permuted
    int d = idx >> 10, jp = idx & 1023;
    int u = jp >> 2, g = jp & 3, j = d * 1024 + g * 256 + u;
    b1p[idx] = bih1[j] + bhh1[j];
    return;
  }
  idx -= 2048;
  if (idx < 524288) { w1f[idx] = (_Float16)W1[idx]; return; }
  idx -= 524288;
  if (idx < 524288) { w2f[idx] = (_Float16)W2[idx]; return; }
  idx -= 524288;
  if (idx < 524288) {                               // W3s = W3[:, :512] + W3[:, 512:]
    int j = idx >> 9, k = idx & 511;
    w3sf[idx] = (_Float16)(W3[(size_t)j * 1024 + k] + W3[(size_t)j * 1024 + 512 + k]);
    return;
  }
}

// ---------------- generic NT GEMM: C[M,N] = A[M,K]f16 * B[N,K]f16 (+bias)(+relu) ----------------
__global__ __launch_bounds__(256) void gemm_nt(
    const _Float16* __restrict__ A, const _Float16* __restrict__ B,
    const float* __restrict__ bias, void* __restrict__ Cout,
    int N, int K, int do_relu, int f16out, int hasbias) {
  __shared__ _Float16 as[64][40];
  __shared__ _Float16 bs[64][40];
  const int tid = threadIdx.x;
  const int w = tid >> 6, lane = tid & 63, q = lane >> 4, m15 = lane & 15;
  const int bm = blockIdx.x * 64, bn = blockIdx.y * 64;
  const int srow = tid >> 2, spart = tid & 3;
  f32x4 acc[4] = {};
  for (int k0 = 0; k0 < K; k0 += 32) {
    if (k0) __syncthreads();
    *(half8*)&as[srow][spart * 8] = *(const half8*)(A + (size_t)(bm + srow) * K + k0 + spart * 8);
    *(half8*)&bs[srow][spart * 8] = *(const half8*)(B + (size_t)(bn + srow) * K + k0 + spart * 8);
    __syncthreads();
    half8 af = *(const half8*)&as[w * 16 + m15][q * 8];
#pragma unroll
    for (int ns = 0; ns < 4; ++ns) {
      half8 bf = *(const half8*)&bs[ns * 16 + m15][q * 8];
      acc[ns] = __builtin_amdgcn_mfma_f32_16x16x32_f16(af, bf, acc[ns], 0, 0, 0);
    }
  }
#pragma unroll
  for (int ns = 0; ns < 4; ++ns) {
    int gn = bn + ns * 16 + m15;
    float bv = hasbias ? bias[gn] : 0.f;
#pragma unroll
    for (int r = 0; r < 4; ++r) {
      int gm = bm + w * 16 + q * 4 + r;
      float v = acc[ns][r] + bv;
      if (do_relu) v = fmaxf(v, 0.f);
      if (f16out) ((_Float16*)Cout)[(size_t)gm * N + gn] = (_Float16)v;
      else ((float*)Cout)[(size_t)gm * N + gn] = v;
    }
  }
}

// ---------------- recurrent layer: 8 blocks = (dir x quarter), 512 threads ----------------
// Block (d, mq) owns units [mq*64, mq*64+64) of direction d: M-tiles mq*16 .. mq*16+15.
// Per lane only 2 tiles x 8 kc = 16 weight frags = 64 VGPRs -> no spill possible.
// Cross-CU h exchange: self-validating 32-bit words (step_tag<<16 | f16 h) via RELAXED
// agent-scope atomics only — NO fences, NO acquire/release (R1's buffer_inv/wbl2 killer).
// Parity double-buffer; a block can lead partners by at most 1 step (publish of s+2
// requires all partners' s+1), so tag-in-word is sufficient.
#define MFMAF(Wf, Bf, Acc) __builtin_amdgcn_mfma_f32_16x16x32_f16((Wf), (Bf), (Acc), 0, 0, 0)
__global__ __launch_bounds__(512, 1) void lstm_layer(
    const half8* __restrict__ wgt,   // this layer's packed Whh (pre-offset)
    const float* __restrict__ P,     // [2 dir][4096 row][1024 jp]  (jp = u*4 + gate)
    _Float16* __restrict__ Hout,     // [4096][512]  (row = n*2048+t, col = d*256+u)
    unsigned* __restrict__ xg,       // [2 par][2 d][4 q][2 chain][64] tagged words
    int tagbase) {                   // layer-unique tag offset (never 0xAAAA)
  __shared__ _Float16 hbuf[2 * 2 * 288];            // [buf][chain][288] (288: bank split)
  __shared__ float4 gbuf[2 * 64];                   // [chain][unit_local]
  const int bid = blockIdx.x;
  const int d = bid >> 2, mq = bid & 3;
  const int tid = threadIdx.x;
  const int w = tid >> 6, lane = tid & 63;
  const int q = lane >> 4, m15 = lane & 15, n2 = m15 & 1;
  // updater role (waves 0-1): chain = w, unit_local = lane
  const int ug = mq * 64 + lane;                    // global unit for updaters
  // reader role (waves 2-7): 384 lanes <-> 3 partners x 128 words
  const int rr = tid - 128;
  const int rp = rr >> 7, ridx = rr & 127;
  const int srcq = (mq + 1 + rp) & 3;
  const int rchain = ridx >> 6, rul = ridx & 63;

  const half8* wb = wgt + ((size_t)((d * 64 + mq * 16 + w * 2) * 8)) * 64 + lane;
#define WLD(ti, kc) wb[((ti) * 8 + (kc)) * 64]
  half8 WA0 = WLD(0, 0), WA1 = WLD(0, 1), WA2 = WLD(0, 2), WA3 = WLD(0, 3);
  half8 WA4 = WLD(0, 4), WA5 = WLD(0, 5), WA6 = WLD(0, 6), WA7 = WLD(0, 7);
  half8 WB0 = WLD(1, 0), WB1 = WLD(1, 1), WB2 = WLD(1, 2), WB3 = WLD(1, 3);
  half8 WB4 = WLD(1, 4), WB5 = WLD(1, 5), WB6 = WLD(1, 6), WB7 = WLD(1, 7);
  for (int i = tid; i < 1152; i += 512) hbuf[i] = (_Float16)0.f;
  float c = 0.f;
  __syncthreads();

  for (int s = 0; s < 2048; ++s) {
    const int t = d ? (2047 - s) : s;
    const int cur = s & 1, nxt = cur ^ 1, par = (s + 1) & 1;
    float4 pv;
    if (w < 2)  // prefetch input-part for this updater's cell (wave-uniform branch)
      pv = *(const float4*)(P + ((size_t)(d * 4096 + w * 2048 + t)) * 1024 + ug * 4);
    const _Float16* hb = hbuf + (cur * 2 + n2) * 288 + q * 8;
    f32x4 acc0 = {}, acc1 = {};
#define STEPKC(kc) { half8 bf = *(const half8*)(hb + (kc) * 32);  \
    acc0 = MFMAF(WA##kc, bf, acc0); acc1 = MFMAF(WB##kc, bf, acc1); }
    STEPKC(0) STEPKC(1) STEPKC(2) STEPKC(3) STEPKC(4) STEPKC(5) STEPKC(6) STEPKC(7)
    if (m15 < 2) {   // task lanes: accN holds 4 gates of unit (w*2+N)*4+q, chain m15
      gbuf[m15 * 64 + (w * 2 + 0) * 4 + q] = make_float4(acc0[0], acc0[1], acc0[2], acc0[3]);
      gbuf[m15 * 64 + (w * 2 + 1) * 4 + q] = make_float4(acc1[0], acc1[1], acc1[2], acc1[3]);
    }
    __syncthreads();
    const unsigned tag = (unsigned)(tagbase + s + 1);
    if (w < 2) {     // updaters: one (chain=w, unit=lane) cell each, c in-register
      float4 g = gbuf[w * 64 + lane];
      float xi = g.x + pv.x, xf = g.y + pv.y, xgg = g.z + pv.z, xo = g.w + pv.w;
      float cn = sigf(xf) * c + sigf(xi) * tanhf_(xgg);
      c = cn;
      float h = sigf(xo) * tanhf_(cn);
      _Float16 h16 = (_Float16)h;
      Hout[(size_t)(w * 2048 + t) * 512 + d * 256 + ug] = h16;
      if (s < 2047) {
        hbuf[(nxt * 2 + w) * 288 + ug] = h16;
        unsigned word = (tag << 16) | (unsigned)__builtin_bit_cast(unsigned short, h16);
        __hip_atomic_store(&xg[(((par * 2 + d) * 4 + mq) * 2 + w) * 64 + lane], word,
                           __ATOMIC_RELAXED, AGENT);
      }
    } else if (s < 2047) {  // readers: spin on one remote tagged word each
      unsigned* src = &xg[(((par * 2 + d) * 4 + srcq) * 2 + rchain) * 64 + rul];
      unsigned word = __hip_atomic_load(src, __ATOMIC_RELAXED, AGENT);
      while ((word >> 16) != tag) word = __hip_atomic_load(src, __ATOMIC_RELAXED, AGENT);
      hbuf[(nxt * 2 + rchain) * 288 + srcq * 64 + rul] =
          __builtin_bit_cast(_Float16, (unsigned short)(word & 0xffffu));
    }
    __syncthreads();
  }
}

// ---------------- pair scorer: one wave per pair ----------------
__global__ __launch_bounds__(256) void pair_kernel(
    const float* __restrict__ S, const int* __restrict__ pair_r, const int* __restrict__ pair_l,
    const float* __restrict__ b3, const float* __restrict__ Wout, const float* __restrict__ bout,
    float* __restrict__ out) {
  const int wid = blockIdx.x * 4 + (threadIdx.x >> 6);
  const int lane = threadIdx.x & 63;
  const int r = pair_r[wid], l = pair_l[wid];
  const float* sr = S + (size_t)r * 1024;
  const float* sl = S + (size_t)(2048 + l) * 1024;
  float a0 = 0.f, a1 = 0.f;
#pragma unroll
  for (int cch = 0; cch < 4; ++cch) {
    int j = cch * 256 + lane * 4;
    float4 vr = *(const float4*)(sr + j);
    float4 vl = *(const float4*)(sl + j);
    float4 bb = *(const float4*)(b3 + j);
    float4 w0 = *(const float4*)(Wout + j);
    float4 w1 = *(const float4*)(Wout + 1024 + j);
    float v;
    v = fmaxf(0.f, 0.5f * (vr.x + vl.x) + bb.x); a0 += v * w0.x; a1 += v * w1.x;
    v = fmaxf(0.f, 0.5f * (vr.y + vl.y) + bb.y); a0 += v * w0.y; a1 += v * w1.y;
    v = fmaxf(0.f, 0.5f * (vr.z + vl.z) + bb.z); a0 += v * w0.z; a1 += v * w1.z;
    v = fmaxf(0.f, 0.5f * (vr.w + vl.w) + bb.w); a0 += v * w0.w; a1 += v * w1.w;
  }
#pragma unroll
  for (int off = 32; off; off >>= 1) {
    a0 += __shfl_xor(a0, off, 64);
    a1 += __shfl_xor(a1, off, 64);
  }
  if (lane == 0) {
    float l0 = a0 + bout[0], l1 = a1 + bout[1];
    float m = fmaxf(l0, l1);
    float lse = m + logf(__expf(l0 - m) + __expf(l1 - m));
    out[(size_t)wid * 2] = l0 - lse;
    out[(size_t)wid * 2 + 1] = l1 - lse;
  }
}

extern "C" void kernel_launch(void* const* d_in, const int* in_sizes, int n_in,
                              void* d_out, int out_size, void* d_ws, size_t ws_size,
                              hipStream_t stream) {
  (void)in_sizes; (void)n_in; (void)out_size;
  const float* v_r  = (const float*)d_in[0];
  const float* v_l  = (const float*)d_in[1];
  const int* pair_r = (const int*)d_in[2];
  const int* pair_l = (const int*)d_in[3];
  const float* Wih0 = (const float*)d_in[4];
  const float* Whh0 = (const float*)d_in[5];
  const float* bih0 = (const float*)d_in[6];
  const float* bhh0 = (const float*)d_in[7];
  const float* Wih1 = (const float*)d_in[8];
  const float* Whh1 = (const float*)d_in[9];
  const float* bih1 = (const float*)d_in[10];
  const float* bhh1 = (const float*)d_in[11];
  const float* W1   = (const float*)d_in[12];
  const float* b1   = (const float*)d_in[13];
  const float* W2   = (const float*)d_in[14];
  const float* b2   = (const float*)d_in[15];
  const float* W3   = (const float*)d_in[16];
  const float* b3   = (const float*)d_in[17];
  const float* Wout = (const float*)d_in[18];
  const float* bout = (const float*)d_in[19];

  if (ws_size < WS_NEED) return;
  char* ws = (char*)d_ws;
  half8* wgt      = (half8*)(ws + O_WGT);
  _Float16* xf16  = (_Float16*)(ws + O_XF16);
  _Float16* wih0p = (_Float16*)(ws + O_WIH0P);
  float* b0p      = (float*)(ws + O_B0P);
  _Float16* wih1p = (_Float16*)(ws + O_WIH1P);
  float* b1p      = (float*)(ws + O_B1P);
  _Float16* w1f   = (_Float16*)(ws + O_W1F);
  _Float16* w2f   = (_Float16*)(ws + O_W2F);
  _Float16* w3sf  = (_Float16*)(ws + O_W3SF);
  float* p0       = (float*)(ws + O_P0);
  _Float16* h0    = (_Float16*)(ws + O_H0);
  float* p1       = (float*)(ws + O_P1);
  _Float16* h1    = (_Float16*)(ws + O_H1);
  _Float16* m1    = (_Float16*)(ws + O_M1);
  _Float16* e     = (_Float16*)(ws + O_E);
  float* sbuf     = (float*)(ws + O_S);
  unsigned* xg    = (unsigned*)(ws + O_XG);

  pack_whh<<<512, 256, 0, stream>>>(Whh0, Whh1, wgt);
  pack_misc<<<11024, 256, 0, stream>>>(v_r, v_l, Wih0, bih0, bhh0, Wih1, bih1, bhh1,
                                       W1, W2, W3, xf16, wih0p, b0p, wih1p, b1p, w1f, w2f, w3sf);
  // layer-0 input parts (both chains stacked as 4096 rows)
  gemm_nt<<<dim3(64, 16), 256, 0, stream>>>(xf16, wih0p, b0p, p0, 1024, 32, 0, 0, 1);
  gemm_nt<<<dim3(64, 16), 256, 0, stream>>>(xf16, wih0p + 32768, b0p + 1024,
                                            p0 + (size_t)4096 * 1024, 1024, 32, 0, 0, 1);
  lstm_layer<<<8, 512, 0, stream>>>(wgt, p0, h0, xg, 4096);
  // layer-1 input parts
  gemm_nt<<<dim3(64, 16), 256, 0, stream>>>(h0, wih1p, b1p, p1, 1024, 512, 0, 0, 1);
  gemm_nt<<<dim3(64, 16), 256, 0, stream>>>(h0, wih1p + 524288, b1p + 1024,
                                            p1 + (size_t)4096 * 1024, 1024, 512, 0, 0, 1);
  lstm_layer<<<8, 512, 0, stream>>>(wgt + 65536, p1, h1, xg, 8192);
  // MLP + symmetrized pair rep precompute
  gemm_nt<<<dim3(64, 16), 256, 0, stream>>>(h1, w1f, b1, m1, 1024, 512, 1, 1, 1);
  gemm_nt<<<dim3(64, 8), 256, 0, stream>>>(m1, w2f, b2, e, 512, 1024, 1, 1, 1);
  gemm_nt<<<dim3(64, 16), 256, 0, stream>>>(e, w3sf, nullptr, sbuf, 1024, 512, 0, 0, 0);
  pair_kernel<<<16384, 256, 0, stream>>>(sbuf, pair_r, pair_l, b3, Wout, bout, (float*)d_out);
}